// Round 2
// baseline (1291.508 us; speedup 1.0000x reference)
//
#include <hip/hip_runtime.h>
#include <hip/hip_bf16.h>

// ---------------- graph prep kernels ----------------

__global__ void count_deg_k(const int* __restrict__ col,
                            unsigned int* __restrict__ deg, int E) {
    int e = blockIdx.x * blockDim.x + threadIdx.x;
    if (e < E) atomicAdd(&deg[col[e]], 1u);
}

__global__ void dis_k(const unsigned int* __restrict__ deg,
                      float* __restrict__ dis, int N) {
    int i = blockIdx.x * blockDim.x + threadIdx.x;
    if (i < N) dis[i] = rsqrtf((float)(deg[i] + 1u));  // +1 self-loop
}

// exclusive scan of deg -> row_ptr (3-kernel scheme, 1024 elems/block)
__global__ void scan1_k(const unsigned int* __restrict__ deg,
                        int* __restrict__ out, int* __restrict__ bsum, int N) {
    __shared__ int lds[256];
    int t = threadIdx.x;
    int base = blockIdx.x * 1024 + t * 4;
    int v0 = (base + 0 < N) ? (int)deg[base + 0] : 0;
    int v1 = (base + 1 < N) ? (int)deg[base + 1] : 0;
    int v2 = (base + 2 < N) ? (int)deg[base + 2] : 0;
    int v3 = (base + 3 < N) ? (int)deg[base + 3] : 0;
    lds[t] = v0 + v1 + v2 + v3;
    __syncthreads();
    for (int off = 1; off < 256; off <<= 1) {
        int x = lds[t];
        int y = (t >= off) ? lds[t - off] : 0;
        __syncthreads();
        lds[t] = x + y;
        __syncthreads();
    }
    int excl = (t == 0) ? 0 : lds[t - 1];
    if (base + 0 < N) out[base + 0] = excl;
    excl += v0;
    if (base + 1 < N) out[base + 1] = excl;
    excl += v1;
    if (base + 2 < N) out[base + 2] = excl;
    excl += v2;
    if (base + 3 < N) out[base + 3] = excl;
    if (t == 255) bsum[blockIdx.x] = lds[255];
}

__global__ void scan2_k(const int* __restrict__ bsum, int* __restrict__ boff, int nb) {
    __shared__ int lds[256];
    int t = threadIdx.x;
    lds[t] = (t < nb) ? bsum[t] : 0;
    __syncthreads();
    for (int off = 1; off < 256; off <<= 1) {
        int x = lds[t];
        int y = (t >= off) ? lds[t - off] : 0;
        __syncthreads();
        lds[t] = x + y;
        __syncthreads();
    }
    boff[t] = (t == 0) ? 0 : lds[t - 1];
}

__global__ void scan3_k(int* __restrict__ row_ptr, int* __restrict__ cursor,
                        const int* __restrict__ boff, int N, int E) {
    int i = blockIdx.x * blockDim.x + threadIdx.x;
    if (i < N) {
        int v = row_ptr[i] + boff[i >> 10];
        row_ptr[i] = v;
        cursor[i]  = v;
    }
    if (i == N) row_ptr[N] = E;
}

__global__ void fill_k(const int* __restrict__ row,
                       const int* __restrict__ col,
                       int* __restrict__ cursor, int* __restrict__ csr_row, int E) {
    int e = blockIdx.x * blockDim.x + threadIdx.x;
    if (e < E) {
        int c = col[e];
        int p = atomicAdd(&cursor[c], 1);
        csr_row[p] = row[e];
    }
}

__global__ void cnt_k(const int* __restrict__ batch,
                      unsigned int* __restrict__ cnt, int N) {
    int i = blockIdx.x * blockDim.x + threadIdx.x;
    if (i < N) atomicAdd(&cnt[batch[i]], 1u);
}

// ---------------- dense transform: H = X @ W (f32, K=128) ----------------
// 64 rows x 128 cols per block, 256 threads, 4x8 per thread, BK=64.
__global__ __launch_bounds__(256) void gemm64_k(const float* __restrict__ X,
                                                const float* __restrict__ W,
                                                float* __restrict__ H, int N) {
    __shared__ float Wl[64 * 128];
    __shared__ float Xl[64 * 65];
    int t = threadIdx.x;
    int row0 = blockIdx.x * 64;
    int tx = t & 15, ty = t >> 4;
    float acc[4][8];
#pragma unroll
    for (int i = 0; i < 4; ++i)
#pragma unroll
        for (int j = 0; j < 8; ++j) acc[i][j] = 0.0f;

    for (int k0 = 0; k0 < 128; k0 += 64) {
#pragma unroll
        for (int i = 0; i < 8; ++i) {  // W slice [64][128]
            int e = i * 256 + t;
            int r = e >> 5, c = (e & 31) << 2;
            *(float4*)&Wl[r * 128 + c] = *(const float4*)&W[(size_t)(k0 + r) * 128 + c];
        }
#pragma unroll
        for (int i = 0; i < 4; ++i) {  // X tile [64][64]
            int e = i * 256 + t;
            int r = e >> 4, c = (e & 15) << 2;
            int row = row0 + r;
            float4 v = (row < N) ? *(const float4*)&X[(size_t)row * 128 + k0 + c]
                                 : make_float4(0.f, 0.f, 0.f, 0.f);
            Xl[r * 65 + c + 0] = v.x;
            Xl[r * 65 + c + 1] = v.y;
            Xl[r * 65 + c + 2] = v.z;
            Xl[r * 65 + c + 3] = v.w;
        }
        __syncthreads();
#pragma unroll 4
        for (int k = 0; k < 64; ++k) {
            float4 w0 = *(float4*)&Wl[k * 128 + tx * 8];
            float4 w1 = *(float4*)&Wl[k * 128 + tx * 8 + 4];
#pragma unroll
            for (int i = 0; i < 4; ++i) {
                float xv = Xl[(ty * 4 + i) * 65 + k];
                acc[i][0] = fmaf(xv, w0.x, acc[i][0]);
                acc[i][1] = fmaf(xv, w0.y, acc[i][1]);
                acc[i][2] = fmaf(xv, w0.z, acc[i][2]);
                acc[i][3] = fmaf(xv, w0.w, acc[i][3]);
                acc[i][4] = fmaf(xv, w1.x, acc[i][4]);
                acc[i][5] = fmaf(xv, w1.y, acc[i][5]);
                acc[i][6] = fmaf(xv, w1.z, acc[i][6]);
                acc[i][7] = fmaf(xv, w1.w, acc[i][7]);
            }
        }
        __syncthreads();
    }
#pragma unroll
    for (int i = 0; i < 4; ++i) {
        int row = row0 + ty * 4 + i;
        if (row < N) {
            float4 o0 = make_float4(acc[i][0], acc[i][1], acc[i][2], acc[i][3]);
            float4 o1 = make_float4(acc[i][4], acc[i][5], acc[i][6], acc[i][7]);
            *(float4*)&H[(size_t)row * 128 + tx * 8 + 0] = o0;
            *(float4*)&H[(size_t)row * 128 + tx * 8 + 4] = o1;
        }
    }
}

// ---------------- aggregation: out[i] = relu(di*(sum_src ds*h[src] + di*h[i]) + b)
// one wave per node; lane handles 2 feature floats (float2 = coalesced 512B/wave)
__global__ __launch_bounds__(256) void agg_k(const float* __restrict__ Hd,
                                             const int* __restrict__ row_ptr,
                                             const int* __restrict__ csr_row,
                                             const float* __restrict__ dis,
                                             const float* __restrict__ bias,
                                             float* __restrict__ Hout, int N) {
    int wid  = (int)((blockIdx.x * (size_t)blockDim.x + threadIdx.x) >> 6);
    int lane = threadIdx.x & 63;
    if (wid >= N) return;
    int beg = row_ptr[wid], end = row_ptr[wid + 1];
    float di = dis[wid];
    float2 hs = *(const float2*)(Hd + (size_t)wid * 128 + lane * 2);
    float ax = di * hs.x, ay = di * hs.y;  // self-loop term (gets *di again below)
    for (int j = beg; j < end; ++j) {
        int src  = csr_row[j];
        float ds = dis[src];
        float2 hv = *(const float2*)(Hd + (size_t)src * 128 + lane * 2);
        ax = fmaf(ds, hv.x, ax);
        ay = fmaf(ds, hv.y, ay);
    }
    float2 b = *(const float2*)(bias + lane * 2);
    float2 o;
    o.x = fmaxf(fmaf(di, ax, b.x), 0.0f);
    o.y = fmaxf(fmaf(di, ay, b.y), 0.0f);
    *(float2*)(Hout + (size_t)wid * 128 + lane * 2) = o;
}

// ---------------- pooling ----------------
__global__ __launch_bounds__(256) void pool_k(const float* __restrict__ H,
                                              const int* __restrict__ batch,
                                              float* __restrict__ out, int N) {
    int wid  = (int)((blockIdx.x * (size_t)blockDim.x + threadIdx.x) >> 6);
    int lane = threadIdx.x & 63;
    if (wid >= N) return;
    int g = batch[wid];
    float2 v = *(const float2*)(H + (size_t)wid * 128 + lane * 2);
    atomicAdd(&out[(size_t)g * 128 + lane * 2 + 0], v.x);
    atomicAdd(&out[(size_t)g * 128 + lane * 2 + 1], v.y);
}

__global__ void fin_k(float* __restrict__ out, const unsigned int* __restrict__ cnt,
                      int total) {
    int i = blockIdx.x * blockDim.x + threadIdx.x;
    if (i < total) out[i] = out[i] / fmaxf((float)cnt[i >> 7], 1.0f);
}

// ---------------- launch ----------------
extern "C" void kernel_launch(void* const* d_in, const int* in_sizes, int n_in,
                              void* d_out, int out_size, void* d_ws, size_t ws_size,
                              hipStream_t stream) {
    const float* x  = (const float*)d_in[0];
    const float* W1 = (const float*)d_in[1]; const float* b1 = (const float*)d_in[2];
    const float* W2 = (const float*)d_in[3]; const float* b2 = (const float*)d_in[4];
    const float* W3 = (const float*)d_in[5]; const float* b3 = (const float*)d_in[6];
    const float* W4 = (const float*)d_in[7]; const float* b4 = (const float*)d_in[8];
    const int* eidx  = (const int*)d_in[9];   // harness delivers integer inputs as int32
    const int* batch = (const int*)d_in[10];

    int N = in_sizes[0] / 128;
    int E = in_sizes[9] / 2;
    const int* erow = eidx;      // source
    const int* ecol = eidx + E;  // target

    char* ws = (char*)d_ws;
    size_t off = 0;
    auto alloc = [&](size_t bytes) -> void* {
        void* p = ws + off;
        off = (off + bytes + 255) & ~(size_t)255;
        return p;
    };
    unsigned int* deg    = (unsigned int*)alloc((size_t)N * 4);
    float*        dis    = (float*)alloc((size_t)N * 4);
    int*          rowp   = (int*)alloc((size_t)(N + 1) * 4);
    int*          cursor = (int*)alloc((size_t)N * 4);
    int*          bsum   = (int*)alloc(1024);
    int*          boff   = (int*)alloc(1024);
    unsigned int* cnt    = (unsigned int*)alloc(2048 * 4);
    int*          csr    = (int*)alloc((size_t)E * 4);
    float*        hA     = (float*)alloc((size_t)N * 128 * 4);
    float*        hB     = (float*)alloc((size_t)N * 128 * 4);
    (void)ws_size;

    hipMemsetAsync(deg, 0, (size_t)N * 4, stream);
    hipMemsetAsync(cnt, 0, 2048 * 4, stream);
    hipMemsetAsync(d_out, 0, (size_t)out_size * 4, stream);

    const int B = 256;
    count_deg_k<<<(E + B - 1) / B, B, 0, stream>>>(ecol, deg, E);
    dis_k<<<(N + B - 1) / B, B, 0, stream>>>(deg, dis, N);
    int nb = (N + 1023) / 1024;
    scan1_k<<<nb, 256, 0, stream>>>(deg, rowp, bsum, N);
    scan2_k<<<1, 256, 0, stream>>>(bsum, boff, nb);
    scan3_k<<<(N + 1 + B - 1) / B, B, 0, stream>>>(rowp, cursor, boff, N, E);
    fill_k<<<(E + B - 1) / B, B, 0, stream>>>(erow, ecol, cursor, csr, E);
    cnt_k<<<(N + B - 1) / B, B, 0, stream>>>(batch, cnt, N);

    int gb = (N + 63) / 64;   // gemm blocks
    int ab = (N + 3) / 4;     // 4 waves (nodes) per 256-thread block

    gemm64_k<<<gb, 256, 0, stream>>>(x, W1, hA, N);
    agg_k<<<ab, 256, 0, stream>>>(hA, rowp, csr, dis, b1, hB, N);
    gemm64_k<<<gb, 256, 0, stream>>>(hB, W2, hA, N);
    agg_k<<<ab, 256, 0, stream>>>(hA, rowp, csr, dis, b2, hB, N);
    gemm64_k<<<gb, 256, 0, stream>>>(hB, W3, hA, N);
    agg_k<<<ab, 256, 0, stream>>>(hA, rowp, csr, dis, b3, hB, N);
    gemm64_k<<<gb, 256, 0, stream>>>(hB, W4, hA, N);
    agg_k<<<ab, 256, 0, stream>>>(hA, rowp, csr, dis, b4, hB, N);

    pool_k<<<ab, 256, 0, stream>>>(hB, batch, (float*)d_out, N);
    fin_k<<<(out_size + B - 1) / B, B, 0, stream>>>((float*)d_out, cnt, out_size);
}

// Round 4
// 774.616 us; speedup vs baseline: 1.6673x; 1.6673x over previous
//
#include <hip/hip_runtime.h>
#include <hip/hip_bf16.h>
#include <hip/hip_fp16.h>

typedef _Float16 half8 __attribute__((ext_vector_type(8)));
typedef _Float16 h2    __attribute__((ext_vector_type(2)));
typedef float    f32x4 __attribute__((ext_vector_type(4)));

// ---------------- graph prep kernels ----------------

__global__ void count_deg_k(const int* __restrict__ col,
                            unsigned int* __restrict__ deg, int E) {
    int e = blockIdx.x * blockDim.x + threadIdx.x;
    if (e < E) atomicAdd(&deg[col[e]], 1u);
}

__global__ void dis_k(const unsigned int* __restrict__ deg,
                      float* __restrict__ dis, int N) {
    int i = blockIdx.x * blockDim.x + threadIdx.x;
    if (i < N) dis[i] = rsqrtf((float)(deg[i] + 1u));  // +1 self-loop
}

__global__ void scan1_k(const unsigned int* __restrict__ deg,
                        int* __restrict__ out, int* __restrict__ bsum, int N) {
    __shared__ int lds[256];
    int t = threadIdx.x;
    int base = blockIdx.x * 1024 + t * 4;
    int v0 = (base + 0 < N) ? (int)deg[base + 0] : 0;
    int v1 = (base + 1 < N) ? (int)deg[base + 1] : 0;
    int v2 = (base + 2 < N) ? (int)deg[base + 2] : 0;
    int v3 = (base + 3 < N) ? (int)deg[base + 3] : 0;
    lds[t] = v0 + v1 + v2 + v3;
    __syncthreads();
    for (int off = 1; off < 256; off <<= 1) {
        int x = lds[t];
        int y = (t >= off) ? lds[t - off] : 0;
        __syncthreads();
        lds[t] = x + y;
        __syncthreads();
    }
    int excl = (t == 0) ? 0 : lds[t - 1];
    if (base + 0 < N) out[base + 0] = excl;
    excl += v0;
    if (base + 1 < N) out[base + 1] = excl;
    excl += v1;
    if (base + 2 < N) out[base + 2] = excl;
    excl += v2;
    if (base + 3 < N) out[base + 3] = excl;
    if (t == 255) bsum[blockIdx.x] = lds[255];
}

__global__ void scan2_k(const int* __restrict__ bsum, int* __restrict__ boff, int nb) {
    __shared__ int lds[256];
    int t = threadIdx.x;
    lds[t] = (t < nb) ? bsum[t] : 0;
    __syncthreads();
    for (int off = 1; off < 256; off <<= 1) {
        int x = lds[t];
        int y = (t >= off) ? lds[t - off] : 0;
        __syncthreads();
        lds[t] = x + y;
        __syncthreads();
    }
    boff[t] = (t == 0) ? 0 : lds[t - 1];
}

__global__ void scan3_k(int* __restrict__ row_ptr, int* __restrict__ cursor,
                        const int* __restrict__ boff, int N, int E) {
    int i = blockIdx.x * blockDim.x + threadIdx.x;
    if (i < N) {
        int v = row_ptr[i] + boff[i >> 10];
        row_ptr[i] = v;
        cursor[i]  = v;
    }
    if (i == N) row_ptr[N] = E;
}

__global__ void fill_k(const int* __restrict__ row,
                       const int* __restrict__ col,
                       int* __restrict__ cursor, int* __restrict__ csr_row, int E) {
    int e = blockIdx.x * blockDim.x + threadIdx.x;
    if (e < E) {
        int c = col[e];
        int p = atomicAdd(&cursor[c], 1);
        csr_row[p] = row[e];
    }
}

__global__ void cnt_k(const int* __restrict__ batch,
                      unsigned int* __restrict__ cnt, int N) {
    int i = blockIdx.x * blockDim.x + threadIdx.x;
    if (i < N) atomicAdd(&cnt[batch[i]], 1u);
}

// W[k][n] f32 row-major -> Wt[n][k] f16 (transposed)
__global__ void wtcast_k(const float* __restrict__ W, _Float16* __restrict__ Wt) {
    int t = blockIdx.x * 256 + threadIdx.x;  // 16384
    int k = t >> 7, n = t & 127;
    Wt[n * 128 + k] = (_Float16)W[t];
}

// ---------------- MFMA f16 GEMM: H[r][:] = dis[r] * (A[r][:] @ W) ----------------
// block = 256 threads (4 waves), 128 rows/block, wave = 32 rows (2 m-tiles).
// No LDS: A-frags direct (coalesced 64B segments), Wt-frags from L2.
// mfma_f32_16x16x32_f16 layouts: A: row=l&15, k=(l>>4)*8+j ; B: col=l&15, k=(l>>4)*8+j
// (B read from Wt[n][k] so the load is contiguous); D: col=l&15, row=(l>>4)*4+r.
template<bool F32IN>
__global__ __launch_bounds__(256) void gemm_mfma_k(const void* __restrict__ Ain,
                                                   const _Float16* __restrict__ Wt,
                                                   const float* __restrict__ dis,
                                                   _Float16* __restrict__ H, int N) {
    int wave = threadIdx.x >> 6, l = threadIdx.x & 63;
    int lr = l & 15, lk = l >> 4;
    int row0 = blockIdx.x * 128 + wave * 32;

    half8 a[2][4];
#pragma unroll
    for (int m = 0; m < 2; ++m) {
#pragma unroll
        for (int s = 0; s < 4; ++s) {
            int r = row0 + m * 16 + lr;
            int k0 = s * 32 + lk * 8;
            half8 t;
            if (r < N) {
                if constexpr (F32IN) {
                    const float* ap = (const float*)Ain + (size_t)r * 128 + k0;
                    float4 u0 = *(const float4*)ap;
                    float4 u1 = *(const float4*)(ap + 4);
                    t[0] = (_Float16)u0.x; t[1] = (_Float16)u0.y;
                    t[2] = (_Float16)u0.z; t[3] = (_Float16)u0.w;
                    t[4] = (_Float16)u1.x; t[5] = (_Float16)u1.y;
                    t[6] = (_Float16)u1.z; t[7] = (_Float16)u1.w;
                } else {
                    t = *(const half8*)((const _Float16*)Ain + (size_t)r * 128 + k0);
                }
            } else {
#pragma unroll
                for (int i = 0; i < 8; ++i) t[i] = (_Float16)0.0f;
            }
            a[m][s] = t;
        }
    }

    f32x4 acc[2][8];
#pragma unroll
    for (int m = 0; m < 2; ++m)
#pragma unroll
        for (int nt = 0; nt < 8; ++nt)
#pragma unroll
            for (int r = 0; r < 4; ++r) acc[m][nt][r] = 0.0f;

#pragma unroll
    for (int nt = 0; nt < 8; ++nt) {
        half8 b[4];
#pragma unroll
        for (int s = 0; s < 4; ++s)
            b[s] = *(const half8*)(Wt + (size_t)(nt * 16 + lr) * 128 + s * 32 + lk * 8);
#pragma unroll
        for (int m = 0; m < 2; ++m)
#pragma unroll
            for (int s = 0; s < 4; ++s)
                acc[m][nt] = __builtin_amdgcn_mfma_f32_16x16x32_f16(a[m][s], b[s],
                                                                    acc[m][nt], 0, 0, 0);
    }

#pragma unroll
    for (int m = 0; m < 2; ++m) {
        int   orow[4];
        float dv[4];
#pragma unroll
        for (int r = 0; r < 4; ++r) {
            orow[r] = row0 + m * 16 + lk * 4 + r;
            dv[r]   = (orow[r] < N) ? dis[orow[r]] : 0.0f;
        }
#pragma unroll
        for (int nt = 0; nt < 8; ++nt)
#pragma unroll
            for (int r = 0; r < 4; ++r)
                if (orow[r] < N)
                    H[(size_t)orow[r] * 128 + nt * 16 + lr] =
                        (_Float16)(acc[m][nt][r] * dv[r]);
    }
}

// ---------------- aggregation (fp16 gather, dis pre-folded) ----------------
// h' = dis*h stored by gemm. out = relu(di * (sum_src h'[src] + h'[self]) + b)
// one wave per node, lane = 2 f16 (4B gather, 256B/row). Unroll x4 for MLP.
template<bool POOL>
__global__ __launch_bounds__(256) void agg_h_k(const _Float16* __restrict__ Hd,
                                               const int* __restrict__ row_ptr,
                                               const int* __restrict__ csr_row,
                                               const float* __restrict__ dis,
                                               const float* __restrict__ bias,
                                               _Float16* __restrict__ Hout,
                                               const int* __restrict__ batch,
                                               float* __restrict__ pout, int N) {
    int wid  = (int)((blockIdx.x * (size_t)blockDim.x + threadIdx.x) >> 6);
    int lane = threadIdx.x & 63;
    if (wid >= N) return;
    int beg = row_ptr[wid], end = row_ptr[wid + 1];
    float di = dis[wid];
    const _Float16* hp = Hd + lane * 2;

    h2 self = *(const h2*)(hp + (size_t)wid * 128);
    float ax = (float)self[0], ay = (float)self[1];

    int j = beg;
    for (; j + 4 <= end; j += 4) {
        int s0 = csr_row[j], s1 = csr_row[j + 1], s2 = csr_row[j + 2], s3 = csr_row[j + 3];
        h2 v0 = *(const h2*)(hp + (size_t)s0 * 128);
        h2 v1 = *(const h2*)(hp + (size_t)s1 * 128);
        h2 v2 = *(const h2*)(hp + (size_t)s2 * 128);
        h2 v3 = *(const h2*)(hp + (size_t)s3 * 128);
        ax += (float)v0[0] + (float)v1[0] + (float)v2[0] + (float)v3[0];
        ay += (float)v0[1] + (float)v1[1] + (float)v2[1] + (float)v3[1];
    }
    for (; j < end; ++j) {
        int s = csr_row[j];
        h2 v = *(const h2*)(hp + (size_t)s * 128);
        ax += (float)v[0];
        ay += (float)v[1];
    }

    float bx = bias[lane * 2], by = bias[lane * 2 + 1];
    float ox = fmaxf(fmaf(di, ax, bx), 0.0f);
    float oy = fmaxf(fmaf(di, ay, by), 0.0f);

    if constexpr (POOL) {
        int g = batch[wid];
        atomicAdd(&pout[(size_t)g * 128 + lane * 2 + 0], ox);
        atomicAdd(&pout[(size_t)g * 128 + lane * 2 + 1], oy);
    } else {
        h2 o;
        o[0] = (_Float16)ox;
        o[1] = (_Float16)oy;
        *(h2*)(Hout + (size_t)wid * 128 + lane * 2) = o;
    }
}

__global__ void fin_k(float* __restrict__ out, const unsigned int* __restrict__ cnt,
                      int total) {
    int i = blockIdx.x * blockDim.x + threadIdx.x;
    if (i < total) out[i] = out[i] / fmaxf((float)cnt[i >> 7], 1.0f);
}

// ---------------- launch ----------------
extern "C" void kernel_launch(void* const* d_in, const int* in_sizes, int n_in,
                              void* d_out, int out_size, void* d_ws, size_t ws_size,
                              hipStream_t stream) {
    const float* x  = (const float*)d_in[0];
    const float* W1 = (const float*)d_in[1]; const float* b1 = (const float*)d_in[2];
    const float* W2 = (const float*)d_in[3]; const float* b2 = (const float*)d_in[4];
    const float* W3 = (const float*)d_in[5]; const float* b3 = (const float*)d_in[6];
    const float* W4 = (const float*)d_in[7]; const float* b4 = (const float*)d_in[8];
    const int* eidx  = (const int*)d_in[9];
    const int* batch = (const int*)d_in[10];

    int N = in_sizes[0] / 128;
    int E = in_sizes[9] / 2;
    const int* erow = eidx;      // source
    const int* ecol = eidx + E;  // target

    char* ws = (char*)d_ws;
    size_t off = 0;
    auto alloc = [&](size_t bytes) -> void* {
        void* p = ws + off;
        off = (off + bytes + 255) & ~(size_t)255;
        return p;
    };
    unsigned int* deg    = (unsigned int*)alloc((size_t)N * 4);
    float*        dis    = (float*)alloc((size_t)N * 4);
    int*          rowp   = (int*)alloc((size_t)(N + 1) * 4);
    int*          cursor = (int*)alloc((size_t)N * 4);
    int*          bsum   = (int*)alloc(1024);
    int*          boff   = (int*)alloc(1024);
    unsigned int* cnt    = (unsigned int*)alloc(2048 * 4);
    int*          csr    = (int*)alloc((size_t)E * 4);
    _Float16*     Wt1    = (_Float16*)alloc(128 * 128 * 2);
    _Float16*     Wt2    = (_Float16*)alloc(128 * 128 * 2);
    _Float16*     Wt3    = (_Float16*)alloc(128 * 128 * 2);
    _Float16*     Wt4    = (_Float16*)alloc(128 * 128 * 2);
    _Float16*     hA     = (_Float16*)alloc((size_t)N * 128 * 2);
    _Float16*     hB     = (_Float16*)alloc((size_t)N * 128 * 2);
    (void)ws_size;

    hipMemsetAsync(deg, 0, (size_t)N * 4, stream);
    hipMemsetAsync(cnt, 0, 2048 * 4, stream);
    hipMemsetAsync(d_out, 0, (size_t)out_size * 4, stream);

    const int B = 256;
    count_deg_k<<<(E + B - 1) / B, B, 0, stream>>>(ecol, deg, E);
    dis_k<<<(N + B - 1) / B, B, 0, stream>>>(deg, dis, N);
    int nb = (N + 1023) / 1024;
    scan1_k<<<nb, 256, 0, stream>>>(deg, rowp, bsum, N);
    scan2_k<<<1, 256, 0, stream>>>(bsum, boff, nb);
    scan3_k<<<(N + 1 + B - 1) / B, B, 0, stream>>>(rowp, cursor, boff, N, E);
    fill_k<<<(E + B - 1) / B, B, 0, stream>>>(erow, ecol, cursor, csr, E);
    cnt_k<<<(N + B - 1) / B, B, 0, stream>>>(batch, cnt, N);
    wtcast_k<<<64, 256, 0, stream>>>(W1, Wt1);
    wtcast_k<<<64, 256, 0, stream>>>(W2, Wt2);
    wtcast_k<<<64, 256, 0, stream>>>(W3, Wt3);
    wtcast_k<<<64, 256, 0, stream>>>(W4, Wt4);

    int gb = (N + 127) / 128;  // gemm blocks (128 rows each)
    int ab = (N + 3) / 4;      // 4 waves (nodes) per 256-thread block

    gemm_mfma_k<true ><<<gb, 256, 0, stream>>>(x,  Wt1, dis, hA, N);
    agg_h_k<false><<<ab, 256, 0, stream>>>(hA, rowp, csr, dis, b1, hB, batch, nullptr, N);
    gemm_mfma_k<false><<<gb, 256, 0, stream>>>(hB, Wt2, dis, hA, N);
    agg_h_k<false><<<ab, 256, 0, stream>>>(hA, rowp, csr, dis, b2, hB, batch, nullptr, N);
    gemm_mfma_k<false><<<gb, 256, 0, stream>>>(hB, Wt3, dis, hA, N);
    agg_h_k<false><<<ab, 256, 0, stream>>>(hA, rowp, csr, dis, b3, hB, batch, nullptr, N);
    gemm_mfma_k<false><<<gb, 256, 0, stream>>>(hB, Wt4, dis, hA, N);
    agg_h_k<true ><<<ab, 256, 0, stream>>>(hA, rowp, csr, dis, b4, nullptr, batch,
                                           (float*)d_out, N);

    fin_k<<<(out_size + B - 1) / B, B, 0, stream>>>((float*)d_out, cnt, out_size);
}